// Round 1
// baseline (596.159 us; speedup 1.0000x reference)
//
#include <hip/hip_runtime.h>

// DotProductNonLocalBlock: B=8, C=512, H=W=56 (N=3136), E=256.
// No softmax => attention is associative:
//   embed = Q (K V)/N;  Out = Wo KV^T Wq /N . X + (Wo KV^T bq /N + bo) + X
// Pipeline (per batch):
//   Kp = wk X + bk, Vp = wv X + bv          (in d_out scratch, 51.4 MB)
//   KV = Kp Vp^T                            (split-K=7, fp32 atomics)
//   W2 = wo KV^T / N ; A2 = W2 wq ; a2 = W2 bq + bo
//   Out = A2 X + a2 + X
// ~31 GFLOP total (vs 107 GF + 315 MB attn in the reference form).

#define TILE 64
#define BK 16
#define LDSP (TILE + 4)

__global__ void zero_f4(float4* __restrict__ p, int n4) {
    int i = blockIdx.x * 256 + threadIdx.x;
    if (i < n4) p[i] = make_float4(0.f, 0.f, 0.f, 0.f);
}

// Generic 64x64-tile fp32 GEMM.
//   C[b] = alpha * A[b] * B[b] (+bias[b][m]) (+src[b][m][n]) ; ATOMIC => atomicAdd into C
// A is [M][K] row-major (lda). B is [K][N] (ldb) or, if BT, [N][K] row-major (ldb).
// Batch via blockIdx.z = batch*nSplit + ks (split-K chunk ks, chunk length kLen).
template<bool BT, bool ADD_BIAS, bool ADD_SRC, bool ATOMIC>
__global__ __launch_bounds__(256)
void gemm64(const float* __restrict__ A, long long sA, int lda,
            const float* __restrict__ B, long long sB, int ldb,
            float* __restrict__ C, long long sC, int ldc,
            const float* __restrict__ bias, long long sBias,
            const float* __restrict__ src, long long sSrc, int ldsrc,
            float alpha, int kLen, int nSplit)
{
    __shared__ __align__(16) float As[BK][LDSP];
    __shared__ __align__(16) float Bs[BK][LDSP];

    const int tid = threadIdx.x;
    const int tx = tid & 15;          // n quad
    const int ty = tid >> 4;          // m quad
    const int bz = blockIdx.z;
    const int batch = bz / nSplit;
    const int ks = bz - batch * nSplit;
    const int m0 = blockIdx.y * TILE;
    const int n0 = blockIdx.x * TILE;
    const int k0base = ks * kLen;

    const float* Ab = A + (long long)batch * sA;
    const float* Bb = B + (long long)batch * sB;

    float acc[4][4];
#pragma unroll
    for (int i = 0; i < 4; ++i)
#pragma unroll
        for (int j = 0; j < 4; ++j) acc[i][j] = 0.f;

    // A/BT tile load mapping: one float4 along K per thread
    const int lr = tid >> 2;              // 0..63 (row)
    const int lk4 = (tid & 3) << 2;       // 0,4,8,12 (k offset)
    // normal-B tile load mapping: one float4 along N per thread
    const int bk_ = tid >> 4;             // 0..15 (k)
    const int bn4 = (tid & 15) << 2;      // 0..60 (n offset)

    for (int kt = 0; kt < kLen; kt += BK) {
        const int k0 = k0base + kt;

        float4 av = *(const float4*)&Ab[(long long)(m0 + lr) * lda + k0 + lk4];
        float4 bv;
        if (BT) bv = *(const float4*)&Bb[(long long)(n0 + lr) * ldb + k0 + lk4];
        else    bv = *(const float4*)&Bb[(long long)(k0 + bk_) * ldb + n0 + bn4];

        __syncthreads();
        As[lk4 + 0][lr] = av.x;
        As[lk4 + 1][lr] = av.y;
        As[lk4 + 2][lr] = av.z;
        As[lk4 + 3][lr] = av.w;
        if (BT) {
            Bs[lk4 + 0][lr] = bv.x;
            Bs[lk4 + 1][lr] = bv.y;
            Bs[lk4 + 2][lr] = bv.z;
            Bs[lk4 + 3][lr] = bv.w;
        } else {
            *(float4*)&Bs[bk_][bn4] = bv;
        }
        __syncthreads();

#pragma unroll
        for (int kk = 0; kk < BK; ++kk) {
            float4 a4 = *(const float4*)&As[kk][ty << 2];
            float4 b4 = *(const float4*)&Bs[kk][tx << 2];
            const float a[4] = {a4.x, a4.y, a4.z, a4.w};
            const float b[4] = {b4.x, b4.y, b4.z, b4.w};
#pragma unroll
            for (int i = 0; i < 4; ++i)
#pragma unroll
                for (int j = 0; j < 4; ++j)
                    acc[i][j] = fmaf(a[i], b[j], acc[i][j]);
        }
    }

    const int mo = m0 + (ty << 2);
    const int no = n0 + (tx << 2);
    float* Cb = C + (long long)batch * sC;

    if (ATOMIC) {
#pragma unroll
        for (int i = 0; i < 4; ++i)
#pragma unroll
            for (int j = 0; j < 4; ++j)
                atomicAdd(&Cb[(long long)(mo + i) * ldc + no + j], acc[i][j] * alpha);
    } else {
#pragma unroll
        for (int i = 0; i < 4; ++i) {
            float bi = ADD_BIAS ? bias[batch * sBias + mo + i] : 0.f;
            float4 v;
            v.x = fmaf(acc[i][0], alpha, bi);
            v.y = fmaf(acc[i][1], alpha, bi);
            v.z = fmaf(acc[i][2], alpha, bi);
            v.w = fmaf(acc[i][3], alpha, bi);
            if (ADD_SRC) {
                const float* sb = src + (long long)batch * sSrc + (long long)(mo + i) * ldsrc + no;
                v.x += sb[0]; v.y += sb[1]; v.z += sb[2]; v.w += sb[3];
            }
            *(float4*)&Cb[(long long)(mo + i) * ldc + no] = v;
        }
    }
}

// a2[b][c] = dot(W2[b][c][:], bq) + bo[c]   (W2 already carries the 1/N scale)
__global__ __launch_bounds__(256)
void a2_kernel(const float* __restrict__ W2, const float* __restrict__ bq,
               const float* __restrict__ bo, float* __restrict__ a2)
{
    int idx = blockIdx.x * 256 + threadIdx.x;   // 0..4095 = b*512 + c
    int c = idx & 511;
    const float4* row = (const float4*)(W2 + (long long)idx * 256);
    const float4* q4 = (const float4*)bq;
    float s = 0.f;
#pragma unroll 4
    for (int e = 0; e < 64; ++e) {
        float4 w = row[e], b = q4[e];
        s = fmaf(w.x, b.x, s); s = fmaf(w.y, b.y, s);
        s = fmaf(w.z, b.z, s); s = fmaf(w.w, b.w, s);
    }
    a2[idx] = s + bo[c];
}

extern "C" void kernel_launch(void* const* d_in, const int* in_sizes, int n_in,
                              void* d_out, int out_size, void* d_ws, size_t ws_size,
                              hipStream_t stream)
{
    const float* x  = (const float*)d_in[0];
    const float* wq = (const float*)d_in[1];
    const float* bq = (const float*)d_in[2];
    const float* wk = (const float*)d_in[3];
    const float* bk = (const float*)d_in[4];
    const float* wv = (const float*)d_in[5];
    const float* bv = (const float*)d_in[6];
    const float* wo = (const float*)d_in[7];
    const float* bo = (const float*)d_in[8];
    float* out = (float*)d_out;
    float* ws  = (float*)d_ws;

    const int C = 512, E = 256, N = 3136;
    const long long xs = (long long)C * N;          // per-batch x / out stride

    // workspace layout (floats): KV | W2 | A2 | a2  (~14.7 MB total)
    float* KV  = ws;                                // 8*256*256
    float* W2  = KV + 8LL * E * E;                  // 8*512*256
    float* A2  = W2 + 8LL * C * E;                  // 8*512*512
    float* a2v = A2 + 8LL * C * C;                  // 8*512

    // Kp/Vp staged in d_out: per batch a [512][3136] block, rows 0..255=Kp, 256..511=Vp
    float* Kp = out;
    float* Vp = out + (long long)E * N;

    // 0) zero KV accumulator (ws is poisoned 0xAA)
    zero_f4<<<dim3(512), dim3(256), 0, stream>>>((float4*)KV, 8 * E * E / 4);

    // 1) Kp = wk x + bk   (M=256, N=3136, K=512)
    gemm64<false, true, false, false><<<dim3(49, 4, 8), 256, 0, stream>>>(
        wk, 0, C, x, xs, N, Kp, xs, N, bk, 0, nullptr, 0, 0, 1.f, C, 1);
    // 2) Vp = wv x + bv
    gemm64<false, true, false, false><<<dim3(49, 4, 8), 256, 0, stream>>>(
        wv, 0, C, x, xs, N, Vp, xs, N, bv, 0, nullptr, 0, 0, 1.f, C, 1);

    // 3) KV += Kp Vp^T  (M=N=256, K=3136, split-K=7, atomics)
    gemm64<true, false, false, true><<<dim3(4, 4, 8 * 7), 256, 0, stream>>>(
        Kp, xs, N, Vp, xs, N, KV, (long long)E * E, E,
        nullptr, 0, nullptr, 0, 0, 1.f, N / 7, 7);

    // 4) W2 = wo KV^T / N  (M=512, N=256, K=256; B^T layout)
    gemm64<true, false, false, false><<<dim3(4, 8, 8), 256, 0, stream>>>(
        wo, 0, E, KV, (long long)E * E, E, W2, (long long)C * E, E,
        nullptr, 0, nullptr, 0, 0, 1.f / (float)N, E, 1);

    // 5) A2 = W2 wq  (M=512, N=512, K=256)
    gemm64<false, false, false, false><<<dim3(8, 8, 8), 256, 0, stream>>>(
        W2, (long long)C * E, E, wq, 0, C, A2, (long long)C * C, C,
        nullptr, 0, nullptr, 0, 0, 1.f, E, 1);

    // 6) a2 = W2 bq + bo
    a2_kernel<<<dim3(16), dim3(256), 0, stream>>>(W2, bq, bo, a2v);

    // 7) out = A2 x + a2 + x  (M=512, N=3136, K=512) — overwrites Kp/Vp scratch
    gemm64<false, true, true, false><<<dim3(49, 8, 8), 256, 0, stream>>>(
        A2, (long long)C * C, C, x, xs, N, out, xs, N,
        a2v, C, x, xs, N, 1.f, C, 1);
}

// Round 2
// 288.764 us; speedup vs baseline: 2.0645x; 2.0645x over previous
//
#include <hip/hip_runtime.h>
#include <hip/hip_bf16.h>

// DotProductNonLocalBlock: B=8, C=512, N=3136 (pad 3200), E=256.
// No softmax => associative:  Out = A2·X + a2 + X, where
//   KVp = [wk;wv]·X (+[bk;bv])  [bf16 MFMA, in d_out scratch]
//   KV  = Kp·Vp^T               [bf16 MFMA, split-K atomics]
//   W2  = wo·KV^T/N ; A2 = W2·wq ; a2 = W2·bq + bo   [small fp32]
//   Out = A2·X + a2 + X         [bf16 MFMA, fp32 residual/bias]

typedef __attribute__((ext_vector_type(8))) __bf16 bf16x8;
typedef __attribute__((ext_vector_type(4))) float floatx4;

struct __align__(8) bh4 { __hip_bfloat16 x, y, z, w; };

__device__ __forceinline__ void load_lds16(const void* g, void* l) {
    __builtin_amdgcn_global_load_lds((const __attribute__((address_space(1))) void*)g,
                                     (__attribute__((address_space(3))) void*)l, 16, 0, 0);
}

__global__ void zero_f4(float4* __restrict__ p, int n4) {
    int i = blockIdx.x * 256 + threadIdx.x;
    if (i < n4) p[i] = make_float4(0.f, 0.f, 0.f, 0.f);
}

// Build Wkv bf16 [512][512] = [wk;wv] and bkv fp32 [512] = [bk;bv]
__global__ __launch_bounds__(256)
void prep(const float* __restrict__ wk, const float* __restrict__ wv,
          const float* __restrict__ bk, const float* __restrict__ bv,
          __hip_bfloat16* __restrict__ Wkvb, float* __restrict__ bkv)
{
    int i = blockIdx.x * 256 + threadIdx.x;          // < 262144
    float v = (i < 131072) ? wk[i] : wv[i - 131072];
    Wkvb[i] = __float2bfloat16(v);
    if (i < 512) bkv[i] = (i < 256) ? bk[i] : bv[i - 256];
}

// x [b][512][3136] fp32 -> xT [b][3200][512] bf16 (pad rows zero). 64x64 tiles.
__global__ __launch_bounds__(256)
void transpose_conv(const float* __restrict__ x, __hip_bfloat16* __restrict__ xT)
{
    __shared__ float t[64][65];
    const int b = blockIdx.z;
    const int n0 = blockIdx.x * 64, c0 = blockIdx.y * 64;
    const int tx = threadIdx.x & 15, ty = threadIdx.x >> 4;
    __hip_bfloat16* xo = xT + (long long)b * 3200 * 512;
    const __hip_bfloat16 z = __float2bfloat16(0.f);
    if (n0 >= 3136) {   // whole tile is padding (3136 = 64*49)
#pragma unroll
        for (int r = 0; r < 4; ++r) {
            bh4 zz = {z, z, z, z};
            *(bh4*)&xo[(long long)(n0 + ty + 16 * r) * 512 + c0 + tx * 4] = zz;
        }
        return;
    }
    const float* xb = x + (long long)b * 512 * 3136;
#pragma unroll
    for (int r = 0; r < 4; ++r) {
        float4 v = *(const float4*)&xb[(long long)(c0 + ty + 16 * r) * 3136 + n0 + tx * 4];
        t[tx * 4 + 0][ty + 16 * r] = v.x;
        t[tx * 4 + 1][ty + 16 * r] = v.y;
        t[tx * 4 + 2][ty + 16 * r] = v.z;
        t[tx * 4 + 3][ty + 16 * r] = v.w;
    }
    __syncthreads();
#pragma unroll
    for (int r = 0; r < 4; ++r) {
        int nn = ty + 16 * r;
        bh4 o;
        o.x = __float2bfloat16(t[nn][tx * 4 + 0]);
        o.y = __float2bfloat16(t[nn][tx * 4 + 1]);
        o.z = __float2bfloat16(t[nn][tx * 4 + 2]);
        o.w = __float2bfloat16(t[nn][tx * 4 + 3]);
        *(bh4*)&xo[(long long)(n0 + nn) * 512 + c0 + tx * 4] = o;
    }
}

__global__ __launch_bounds__(256)
void cvt_bf16_4(const float4* __restrict__ src, bh4* __restrict__ dst, int n4)
{
    int i = blockIdx.x * 256 + threadIdx.x;
    if (i < n4) {
        float4 v = src[i];
        bh4 o = {__float2bfloat16(v.x), __float2bfloat16(v.y),
                 __float2bfloat16(v.z), __float2bfloat16(v.w)};
        dst[i] = o;
    }
}

// MFMA GEMM, both operands K-contiguous ("bt" form): C[m][n] = sum_k A[m][k]*B[n][k].
// 128x128 block tile, BK=32, 4 waves (2x2), each wave 64x64 via 4x4 of 16x16x32 MFMAs.
// MODE 0: bf16 out = acc + bias[m]; cols n>=Nreal forced to 0 (pad).
// MODE 1: fp32 atomicAdd (split-K).
// MODE 2: fp32 out = acc + bias[b][m] + xres[b][m][n], store only n<Nreal.
template<int MODE>
__global__ __launch_bounds__(256)
void mfma_bt(const __hip_bfloat16* __restrict__ A, long long sA, int lda,
             const __hip_bfloat16* __restrict__ B, long long sB, int ldb,
             void* __restrict__ Cp, long long sC, int ldc,
             const float* __restrict__ bias, int sBias,
             const float* __restrict__ xres, long long sX,
             int kLen, int nSplit, int Nreal)
{
    __shared__ __hip_bfloat16 As[128 * 32];
    __shared__ __hip_bfloat16 Bs[128 * 32];
    const int tid = threadIdx.x;
    const int lane = tid & 63;
    const int w = tid >> 6;
    const int wm = (w >> 1) << 6;
    const int wn = (w & 1) << 6;
    const int ln = lane & 15;
    const int hi = lane >> 4;
    const int bz = blockIdx.z;
    const int batch = bz / nSplit;
    const int ks = bz - batch * nSplit;
    const int m0 = blockIdx.y << 7;
    const int n0 = blockIdx.x << 7;
    const long long k0 = (long long)ks * kLen;

    // staging: 512 chunks of 16B per tile; thread covers chunk tid and tid+256
    const int crow = tid >> 2;              // 0..63
    const int ckof = (tid & 3) << 3;        // 0,8,16,24 (elements)

    const __hip_bfloat16* gA = A + batch * sA + (long long)(m0 + crow) * lda + k0 + ckof;
    const __hip_bfloat16* gB = B + batch * sB + (long long)(n0 + crow) * ldb + k0 + ckof;
    const long long stA = 64LL * lda;
    const long long stB = 64LL * ldb;
    __hip_bfloat16* lA = As + tid * 8;
    __hip_bfloat16* lB = Bs + tid * 8;

    floatx4 acc[4][4] = {};

    const int nK = kLen >> 5;
    for (int kt = 0; kt < nK; ++kt) {
        load_lds16(gA, lA);
        load_lds16(gA + stA, lA + 2048);
        load_lds16(gB, lB);
        load_lds16(gB + stB, lB + 2048);
        gA += 32; gB += 32;
        __syncthreads();
        bf16x8 af[4], bfr[4];
#pragma unroll
        for (int i = 0; i < 4; ++i)
            af[i] = *(const bf16x8*)(As + ((wm + i * 16 + ln) << 5) + (hi << 3));
#pragma unroll
        for (int j = 0; j < 4; ++j)
            bfr[j] = *(const bf16x8*)(Bs + ((wn + j * 16 + ln) << 5) + (hi << 3));
#pragma unroll
        for (int i = 0; i < 4; ++i)
#pragma unroll
            for (int j = 0; j < 4; ++j)
                acc[i][j] = __builtin_amdgcn_mfma_f32_16x16x32_bf16(af[i], bfr[j], acc[i][j], 0, 0, 0);
        __syncthreads();
    }

    // C/D layout: col = lane&15, row = (lane>>4)*4 + r  [m89-verified]
    if (MODE == 1) {
        float* Cb = (float*)Cp + batch * sC;
#pragma unroll
        for (int i = 0; i < 4; ++i) {
            int mb = m0 + wm + i * 16 + hi * 4;
#pragma unroll
            for (int j = 0; j < 4; ++j) {
                int nl = n0 + wn + j * 16 + ln;
#pragma unroll
                for (int r = 0; r < 4; ++r)
                    atomicAdd(&Cb[(long long)(mb + r) * ldc + nl], acc[i][j][r]);
            }
        }
    } else if (MODE == 0) {
        __hip_bfloat16* Cb = (__hip_bfloat16*)Cp + batch * sC;
#pragma unroll
        for (int i = 0; i < 4; ++i) {
            int mb = m0 + wm + i * 16 + hi * 4;
#pragma unroll
            for (int r = 0; r < 4; ++r) {
                float bb = bias[mb + r];
#pragma unroll
                for (int j = 0; j < 4; ++j) {
                    int nl = n0 + wn + j * 16 + ln;
                    float v = (nl < Nreal) ? (acc[i][j][r] + bb) : 0.f;
                    Cb[(long long)(mb + r) * ldc + nl] = __float2bfloat16(v);
                }
            }
        }
    } else {
        float* Cb = (float*)Cp + batch * sC;
        const float* xb = xres + batch * sX;
#pragma unroll
        for (int i = 0; i < 4; ++i) {
            int mb = m0 + wm + i * 16 + hi * 4;
#pragma unroll
            for (int r = 0; r < 4; ++r) {
                float bb = bias[batch * sBias + mb + r];
#pragma unroll
                for (int j = 0; j < 4; ++j) {
                    int nl = n0 + wn + j * 16 + ln;
                    if (nl < Nreal) {
                        long long off = (long long)(mb + r) * ldc + nl;
                        Cb[off] = acc[i][j][r] + bb + xb[off];
                    }
                }
            }
        }
    }
}

// ---- fp32 64x64 GEMM (round-1, verified) for the small W2/A2 steps ----
#define TILE 64
#define BK16 16
#define LDSP (TILE + 4)

template<bool BT, bool ADD_BIAS, bool ADD_SRC, bool ATOMIC>
__global__ __launch_bounds__(256)
void gemm64(const float* __restrict__ A, long long sA, int lda,
            const float* __restrict__ B, long long sB, int ldb,
            float* __restrict__ C, long long sC, int ldc,
            const float* __restrict__ bias, long long sBias,
            const float* __restrict__ src, long long sSrc, int ldsrc,
            float alpha, int kLen, int nSplit)
{
    __shared__ __align__(16) float As[BK16][LDSP];
    __shared__ __align__(16) float Bs[BK16][LDSP];
    const int tid = threadIdx.x;
    const int tx = tid & 15, ty = tid >> 4;
    const int bz = blockIdx.z;
    const int batch = bz / nSplit;
    const int ks = bz - batch * nSplit;
    const int m0 = blockIdx.y * TILE, n0 = blockIdx.x * TILE;
    const int k0base = ks * kLen;
    const float* Ab = A + (long long)batch * sA;
    const float* Bb = B + (long long)batch * sB;
    float acc[4][4];
#pragma unroll
    for (int i = 0; i < 4; ++i)
#pragma unroll
        for (int j = 0; j < 4; ++j) acc[i][j] = 0.f;
    const int lr = tid >> 2, lk4 = (tid & 3) << 2;
    const int bk_ = tid >> 4, bn4 = (tid & 15) << 2;
    for (int kt = 0; kt < kLen; kt += BK16) {
        const int k0 = k0base + kt;
        float4 av = *(const float4*)&Ab[(long long)(m0 + lr) * lda + k0 + lk4];
        float4 bv;
        if (BT) bv = *(const float4*)&Bb[(long long)(n0 + lr) * ldb + k0 + lk4];
        else    bv = *(const float4*)&Bb[(long long)(k0 + bk_) * ldb + n0 + bn4];
        __syncthreads();
        As[lk4 + 0][lr] = av.x; As[lk4 + 1][lr] = av.y;
        As[lk4 + 2][lr] = av.z; As[lk4 + 3][lr] = av.w;
        if (BT) {
            Bs[lk4 + 0][lr] = bv.x; Bs[lk4 + 1][lr] = bv.y;
            Bs[lk4 + 2][lr] = bv.z; Bs[lk4 + 3][lr] = bv.w;
        } else {
            *(float4*)&Bs[bk_][bn4] = bv;
        }
        __syncthreads();
#pragma unroll
        for (int kk = 0; kk < BK16; ++kk) {
            float4 a4 = *(const float4*)&As[kk][ty << 2];
            float4 b4 = *(const float4*)&Bs[kk][tx << 2];
            const float a[4] = {a4.x, a4.y, a4.z, a4.w};
            const float b[4] = {b4.x, b4.y, b4.z, b4.w};
#pragma unroll
            for (int i = 0; i < 4; ++i)
#pragma unroll
                for (int j = 0; j < 4; ++j)
                    acc[i][j] = fmaf(a[i], b[j], acc[i][j]);
        }
    }
    const int mo = m0 + (ty << 2), no = n0 + (tx << 2);
    float* Cb = C + (long long)batch * sC;
    if (ATOMIC) {
#pragma unroll
        for (int i = 0; i < 4; ++i)
#pragma unroll
            for (int j = 0; j < 4; ++j)
                atomicAdd(&Cb[(long long)(mo + i) * ldc + no + j], acc[i][j] * alpha);
    } else {
#pragma unroll
        for (int i = 0; i < 4; ++i) {
            float bi = ADD_BIAS ? bias[batch * sBias + mo + i] : 0.f;
            float4 v;
            v.x = fmaf(acc[i][0], alpha, bi);
            v.y = fmaf(acc[i][1], alpha, bi);
            v.z = fmaf(acc[i][2], alpha, bi);
            v.w = fmaf(acc[i][3], alpha, bi);
            if (ADD_SRC) {
                const float* sb = src + (long long)batch * sSrc + (long long)(mo + i) * ldsrc + no;
                v.x += sb[0]; v.y += sb[1]; v.z += sb[2]; v.w += sb[3];
            }
            *(float4*)&Cb[(long long)(mo + i) * ldc + no] = v;
        }
    }
}

__global__ __launch_bounds__(256)
void a2_kernel(const float* __restrict__ W2, const float* __restrict__ bq,
               const float* __restrict__ bo, float* __restrict__ a2)
{
    int idx = blockIdx.x * 256 + threadIdx.x;   // b*512 + c
    int c = idx & 511;
    const float4* row = (const float4*)(W2 + (long long)idx * 256);
    const float4* q4 = (const float4*)bq;
    float s = 0.f;
#pragma unroll 4
    for (int e = 0; e < 64; ++e) {
        float4 w = row[e], b = q4[e];
        s = fmaf(w.x, b.x, s); s = fmaf(w.y, b.y, s);
        s = fmaf(w.z, b.z, s); s = fmaf(w.w, b.w, s);
    }
    a2[idx] = s + bo[c];
}

extern "C" void kernel_launch(void* const* d_in, const int* in_sizes, int n_in,
                              void* d_out, int out_size, void* d_ws, size_t ws_size,
                              hipStream_t stream)
{
    const float* x  = (const float*)d_in[0];
    const float* wq = (const float*)d_in[1];
    const float* bq = (const float*)d_in[2];
    const float* wk = (const float*)d_in[3];
    const float* bk = (const float*)d_in[4];
    const float* wv = (const float*)d_in[5];
    const float* bv = (const float*)d_in[6];
    const float* wo = (const float*)d_in[7];
    const float* bo = (const float*)d_in[8];
    float* out = (float*)d_out;

    const int C = 512, E = 256, N = 3136, Np = 3200;

    // d_out scratch (51.4 MB), all consumed before the final GEMM writes out:
    __hip_bfloat16* KVp = (__hip_bfloat16*)d_out;              // 8*512*3200 bf16 = 26,214,400 B
    float* W2 = (float*)((char*)d_out + 26214400);             // 8*512*256 f32  (4,194,304 B)
    float* A2 = (float*)((char*)d_out + 30408704);             // 8*512*512 f32  (8,388,608 B)

    // ws (needs ~33.1 MB)
    char* wsb = (char*)d_ws;
    __hip_bfloat16* xT   = (__hip_bfloat16*)wsb;               // 26,214,400 B
    float*          KV   = (float*)(wsb + 26214400);           //  2,097,152 B
    __hip_bfloat16* Wkvb = (__hip_bfloat16*)(wsb + 28311552);  //    524,288 B
    float*          bkv  = (float*)(wsb + 28835840);           //      2,048 B
    __hip_bfloat16* A2b  = (__hip_bfloat16*)(wsb + 28837888);  //  4,194,304 B
    float*          a2v  = (float*)(wsb + 33032192);           //     16,384 B

    prep<<<1024, 256, 0, stream>>>(wk, wv, bk, bv, Wkvb, bkv);
    transpose_conv<<<dim3(50, 8, 8), 256, 0, stream>>>(x, xT);
    zero_f4<<<512, 256, 0, stream>>>((float4*)KV, 524288 / 4);

    // KVp = Wkv . X (+bkv)   M=512, Npad=3200, K=512
    mfma_bt<0><<<dim3(25, 4, 8), 256, 0, stream>>>(
        Wkvb, 0, C, xT, (long long)Np * C, C,
        KVp, (long long)C * Np, Np, bkv, 0, nullptr, 0, C, 1, N);

    // KV += Kp . Vp^T   M=N=256, K=3200, split-K=10
    mfma_bt<1><<<dim3(2, 2, 80), 256, 0, stream>>>(
        KVp, (long long)C * Np, Np, KVp + (long long)E * Np, (long long)C * Np, Np,
        KV, (long long)E * E, E, nullptr, 0, nullptr, 0, 320, 10, E);

    // W2 = wo KV^T / N
    gemm64<true, false, false, false><<<dim3(4, 8, 8), 256, 0, stream>>>(
        wo, 0, E, KV, (long long)E * E, E, W2, (long long)C * E, E,
        nullptr, 0, nullptr, 0, 0, 1.f / (float)N, E, 1);

    // A2 = W2 wq
    gemm64<false, false, false, false><<<dim3(8, 8, 8), 256, 0, stream>>>(
        W2, (long long)C * E, E, wq, 0, C, A2, (long long)C * C, C,
        nullptr, 0, nullptr, 0, 0, 1.f, E, 1);

    // a2 = W2 bq + bo
    a2_kernel<<<16, 256, 0, stream>>>(W2, bq, bo, a2v);

    // A2 -> bf16
    cvt_bf16_4<<<2048, 256, 0, stream>>>((const float4*)A2, (bh4*)A2b, 524288);

    // out = A2b . X + a2 + x   M=512, N=3136, K=512
    mfma_bt<2><<<dim3(25, 4, 8), 256, 0, stream>>>(
        A2b, (long long)C * C, C, xT, (long long)Np * C, C,
        out, (long long)C * N, N, a2v, C, x, (long long)C * N, C, 1, N);
}